// Round 6
// baseline (831.612 us; speedup 1.0000x reference)
//
#include <hip/hip_runtime.h>
#include <hip/hip_bf16.h>
#include <cmath>

#define AS_GLOBAL __attribute__((address_space(1)))
#define AS_LDS    __attribute__((address_space(3)))

typedef __attribute__((ext_vector_type(8))) short bf16x8;
typedef __attribute__((ext_vector_type(4))) float f32x4;
typedef unsigned short u16;

__device__ __forceinline__ u16 f2bf(float f) {
  union { __hip_bfloat16 h; u16 u; } cv;
  cv.h = __float2bfloat16(f);
  return cv.u;
}
__device__ __forceinline__ float bf2f(u16 u) {
  union { unsigned u32; float f; } v;
  v.u32 = ((unsigned)u) << 16;
  return v.f;
}

// ---------------------------------------------------------------- prep kernels

__global__ void k_f32_to_bf16(const float* __restrict__ in, u16* __restrict__ out, int n4) {
  int i = blockIdx.x * 256 + threadIdx.x;
  if (i >= n4) return;
  float4 v = ((const float4*)in)[i];
  ushort4 o;
  o.x = f2bf(v.x); o.y = f2bf(v.y); o.z = f2bf(v.z); o.w = f2bf(v.w);
  ((ushort4*)out)[i] = o;
}

// out[n][k] = bf16(in[k][n]), 1024x1024
__global__ void k_transpose_w(const float* __restrict__ in, u16* __restrict__ out) {
  __shared__ float tile[32][33];
  const int tx = threadIdx.x & 31;
  const int ty = threadIdx.x >> 5;  // 0..7
  const int x0 = blockIdx.x * 32, y0 = blockIdx.y * 32;
  #pragma unroll
  for (int i = 0; i < 32; i += 8)
    tile[ty + i][tx] = in[(size_t)(y0 + ty + i) * 1024 + x0 + tx];
  __syncthreads();
  #pragma unroll
  for (int i = 0; i < 32; i += 8)
    out[(size_t)(x0 + ty + i) * 1024 + y0 + tx] = f2bf(tile[tx][ty + i]);
}

// qscale[n] = Q_SCALE * softplus(pds[n % 128]), n in [0,1024)
__global__ void k_qscale(const float* __restrict__ pds, float* __restrict__ qs, float qscale_c) {
  int n = blockIdx.x * 256 + threadIdx.x;
  float s = pds[n & 127];
  qs[n] = qscale_c * log1pf(expf(s));
}

// relkb[p][n] = bf16( sum_k pos[p][k] * Wrel[k][n] )  (wrt = Wrel^T bf16)
__global__ void k_relk(const float* __restrict__ pos, const u16* __restrict__ wrt,
                       u16* __restrict__ relkb) {
  __shared__ float prow[1024];
  const int tid = threadIdx.x;
  const int p = blockIdx.y;
  ((float4*)prow)[tid] = ((const float4*)(pos + (size_t)p * 1024))[tid];
  __syncthreads();
  int nn = blockIdx.x * 256 + tid;
  const u16* wr = wrt + (size_t)nn * 1024;
  float acc = 0.f;
  for (int kk = 0; kk < 1024; kk += 8) {
    ushort4 u0 = *(const ushort4*)(wr + kk);
    ushort4 u1 = *(const ushort4*)(wr + kk + 4);
    acc += bf2f(u0.x) * prow[kk + 0] + bf2f(u0.y) * prow[kk + 1]
         + bf2f(u0.z) * prow[kk + 2] + bf2f(u0.w) * prow[kk + 3]
         + bf2f(u1.x) * prow[kk + 4] + bf2f(u1.y) * prow[kk + 5]
         + bf2f(u1.z) * prow[kk + 6] + bf2f(u1.w) * prow[kk + 7];
  }
  relkb[(size_t)p * 1024 + nn] = f2bf(acc);
}

// ---------------------------------------------------------------- GEMM (256^2, 8-phase T3+T4 schedule)
// BM=BN=256, BK=64. 512 threads = 8 waves (2M x 4N), per-wave 128x64 output.
// LDS 128 KiB dbuf; granule swizzle g^=(row&7) on stage-source AND ds_read (rule 21).
// Counted vmcnt(8)/(6); vmcnt=0 only in the peeled tail (schedule harness-verified r3/r5).
// MFMA16_N: mfma(af,bfb) -> lane holds col=l16, rows quad*4+r (verified r3).
// MFMA16_S: mfma(bfb,af) -> lane holds row=l16, cols quad*4+r (operand swap only;
//           same loads/schedule) -> epilogue becomes ushort4/float4 per (mi,ni).
// qkv mapping: 3x3 supergroup L2-blocking (B-panel reuse distance 12->3 blocks;
// per-XCD working set ~3MB < 4MiB L2). 225 wg/chunk = 25 sgs exactly, bijective.

#define VMCNT(n) do { asm volatile("s_waitcnt vmcnt(" #n ")" ::: "memory"); \
                      __builtin_amdgcn_sched_barrier(0); } while (0)
#define BARF() do { asm volatile("" ::: "memory"); __builtin_amdgcn_s_barrier(); asm volatile("" ::: "memory"); } while (0)
#define GLD(SRC, DST) __builtin_amdgcn_global_load_lds((const AS_GLOBAL u16*)(SRC), (AS_LDS u16*)(DST), 16, 0, 0)
#define LDSA(d) ((AS_LDS char*)&lds[d][0][0])
#define LDSB(d) ((AS_LDS char*)&lds[d][1][0])

#define STAGE_A(d, h, t) do {                                                   \
  GLD(sA0 + (((size_t)(h)) << 6) * K + ((t) << 6), LDSA(d) + dA0 + ((h) << 13)); \
  GLD(sA1 + (((size_t)(h)) << 6) * K + ((t) << 6), LDSA(d) + dA1 + ((h) << 13)); \
} while (0)
#define STAGE_B(d, h, t) do {                                                   \
  GLD(sB0 + (((size_t)(h)) << 5) * K + ((t) << 6), LDSB(d) + dB0 + ((h) << 12)); \
  GLD(sB1 + (((size_t)(h)) << 5) * K + ((t) << 6), LDSB(d) + dB1 + ((h) << 12)); \
} while (0)

#define LOAD_A(d, qm) do {                                                       \
  _Pragma("unroll") for (int mi_ = 0; mi_ < 4; ++mi_) {                          \
    af[mi_][0] = *(const bf16x8*)&lds[d][0][abase + (((qm)*64 + mi_*16) << 6) + gk0]; \
    af[mi_][1] = *(const bf16x8*)&lds[d][0][abase + (((qm)*64 + mi_*16) << 6) + gk1]; \
  } } while (0)
#define LOAD_B(d, qn) do {                                                       \
  _Pragma("unroll") for (int ni_ = 0; ni_ < 2; ++ni_) {                          \
    bfb[ni_][0] = *(const bf16x8*)&lds[d][1][bbase + (((qn)*32 + ni_*16) << 6) + gk0]; \
    bfb[ni_][1] = *(const bf16x8*)&lds[d][1][bbase + (((qn)*32 + ni_*16) << 6) + gk1]; \
  } } while (0)
#define MFMA16_N(qm, qn) do {                                                    \
  __builtin_amdgcn_s_setprio(1);                                                 \
  _Pragma("unroll") for (int mi_ = 0; mi_ < 4; ++mi_)                            \
  _Pragma("unroll") for (int ni_ = 0; ni_ < 2; ++ni_) {                          \
    acc[(qm)*4+mi_][(qn)*2+ni_] = __builtin_amdgcn_mfma_f32_16x16x32_bf16(       \
        af[mi_][0], bfb[ni_][0], acc[(qm)*4+mi_][(qn)*2+ni_], 0, 0, 0);          \
    acc[(qm)*4+mi_][(qn)*2+ni_] = __builtin_amdgcn_mfma_f32_16x16x32_bf16(       \
        af[mi_][1], bfb[ni_][1], acc[(qm)*4+mi_][(qn)*2+ni_], 0, 0, 0);          \
  }                                                                              \
  __builtin_amdgcn_s_setprio(0); } while (0)
#define MFMA16_S(qm, qn) do {                                                    \
  __builtin_amdgcn_s_setprio(1);                                                 \
  _Pragma("unroll") for (int mi_ = 0; mi_ < 4; ++mi_)                            \
  _Pragma("unroll") for (int ni_ = 0; ni_ < 2; ++ni_) {                          \
    acc[(qm)*4+mi_][(qn)*2+ni_] = __builtin_amdgcn_mfma_f32_16x16x32_bf16(       \
        bfb[ni_][0], af[mi_][0], acc[(qm)*4+mi_][(qn)*2+ni_], 0, 0, 0);          \
    acc[(qm)*4+mi_][(qn)*2+ni_] = __builtin_amdgcn_mfma_f32_16x16x32_bf16(       \
        bfb[ni_][1], af[mi_][1], acc[(qm)*4+mi_][(qn)*2+ni_], 0, 0, 0);          \
  }                                                                              \
  __builtin_amdgcn_s_setprio(0); } while (0)

// Full verified pipeline (prologue + steady loop + peeled tail); MM = MFMA16_N/_S.
#define GEMM_MAINLOOP(MM)                                                        \
  STAGE_B(0, 0, 0);  STAGE_A(0, 1, 0);  STAGE_A(0, 0, 0);  STAGE_B(0, 1, 0);     \
  STAGE_B(1, 0, 1);  STAGE_A(1, 1, 1);                                           \
  VMCNT(6);  BARF();                                                             \
  const int nk = K >> 6;                                                         \
  for (int i = 0; i < (nk >> 1) - 1; ++i) {                                      \
    const int t1 = 2 * i + 1, t2 = 2 * i + 2, t3 = 2 * i + 3;                    \
    LOAD_A(0, 0); LOAD_B(0, 0);                                                  \
    STAGE_A(1, 0, t1);                                                           \
    BARF(); MM(0, 0); BARF();                                                    \
    LOAD_A(0, 1);                                                                \
    STAGE_B(1, 1, t1);                                                           \
    BARF(); MM(1, 0); VMCNT(8); BARF();                                          \
    LOAD_B(0, 1);                                                                \
    STAGE_B(0, 0, t2);                                                           \
    BARF(); MM(1, 1); BARF();                                                    \
    LOAD_A(0, 0);                                                                \
    STAGE_A(0, 1, t2);                                                           \
    BARF(); MM(0, 1); VMCNT(6); BARF();                                          \
    LOAD_A(1, 0); LOAD_B(1, 0);                                                  \
    STAGE_A(0, 0, t2);                                                           \
    BARF(); MM(0, 0); BARF();                                                    \
    LOAD_A(1, 1);                                                                \
    STAGE_B(0, 1, t2);                                                           \
    BARF(); MM(1, 0); VMCNT(8); BARF();                                          \
    LOAD_B(1, 1);                                                                \
    STAGE_B(1, 0, t3);                                                           \
    BARF(); MM(1, 1); BARF();                                                    \
    LOAD_A(1, 0);                                                                \
    STAGE_A(1, 1, t3);                                                           \
    BARF(); MM(0, 1); VMCNT(6); BARF();                                          \
  }                                                                              \
  {                                                                              \
    const int t1 = nk - 1;                                                       \
    LOAD_A(0, 0); LOAD_B(0, 0);                                                  \
    STAGE_A(1, 0, t1);                                                           \
    BARF(); MM(0, 0); BARF();                                                    \
    LOAD_A(0, 1);                                                                \
    STAGE_B(1, 1, t1);                                                           \
    BARF(); MM(1, 0); VMCNT(8); BARF();                                          \
    LOAD_B(0, 1);                                                                \
    BARF(); MM(1, 1); BARF();                                                    \
    LOAD_A(0, 0);                                                                \
    BARF(); MM(0, 1); VMCNT(2); BARF();                                          \
    LOAD_A(1, 0); LOAD_B(1, 0);                                                  \
    BARF(); MM(0, 0); BARF();                                                    \
    LOAD_A(1, 1);                                                                \
    BARF(); MM(1, 0); VMCNT(0); BARF();                                          \
    LOAD_B(1, 1);                                                                \
    BARF(); MM(1, 1); BARF();                                                    \
    LOAD_A(1, 0);                                                                \
    BARF(); MM(0, 1);                                                            \
  }

// Per-thread setup; expects m0, n0 already computed.
#define GEMM_SETUP()                                                             \
  const int sx = l16 & 7;                                                        \
  const int gk0 = (quad ^ sx) << 3;                                              \
  const int gk1 = ((4 + quad) ^ sx) << 3;                                        \
  const int abase = (wm * 128 + l16) << 6;                                       \
  const int bbase = (wn * 64 + l16) << 6;                                        \
  const int rl0 = tid >> 3, g0 = tid & 7;                                        \
  const int rl1 = rl0 + 64;                                                      \
  const int swz0 = (g0 ^ (rl0 & 7)) << 3;                                        \
  const int rbA0 = ((rl0 >> 6) << 7) + (rl0 & 63);                               \
  const int rbA1 = ((rl1 >> 6) << 7) + (rl1 & 63);                               \
  const int rbB0 = ((rl0 >> 5) << 6) + (rl0 & 31);                               \
  const int rbB1 = ((rl1 >> 5) << 6) + (rl1 & 31);                               \
  const u16* sA0 = A + (size_t)(m0 + rbA0) * K + swz0;                           \
  const u16* sA1 = A + (size_t)(m0 + rbA1) * K + swz0;                           \
  const u16* sB0 = Bt + (size_t)(n0 + rbB0) * K + swz0;                          \
  const u16* sB1 = Bt + (size_t)(n0 + rbB1) * K + swz0;                          \
  const int dA0 = (rbA0 << 7) + (g0 << 4);                                       \
  const int dA1 = (rbA1 << 7) + (g0 << 4);                                       \
  const int dB0 = (rbB0 << 7) + (g0 << 4);                                       \
  const int dB1 = (rbB1 << 7) + (g0 << 4);                                       \
  f32x4 acc[8][4];                                                               \
  _Pragma("unroll") for (int i = 0; i < 8; ++i)                                  \
    _Pragma("unroll") for (int j = 0; j < 4; ++j) {                              \
      f32x4 z = {0.f, 0.f, 0.f, 0.f};                                            \
      acc[i][j] = z;                                                             \
    }                                                                            \
  bf16x8 af[4][2], bfb[2][2];

// ---- Wpost GEMM: C fp32 row-major [M][N]; swapped layout -> float4 stores.
__global__ __launch_bounds__(512, 2) void k_gemm256(
    const u16* __restrict__ A, const u16* __restrict__ Bt, float* __restrict__ Cout,
    int M, int N, int K) {
  __shared__ __align__(16) u16 lds[2][2][16384];
  const int tid = threadIdx.x;
  const int wave = tid >> 6, lane = tid & 63;
  const int l16 = lane & 15, quad = lane >> 4;
  const int wm = wave >> 2, wn = wave & 3;
  const int q8 = (int)gridDim.x >> 3;
  const int wg = ((int)blockIdx.x & 7) * q8 + ((int)blockIdx.x >> 3);
  const int ntn = N >> 8;
  const int m0 = (wg / ntn) << 8;
  const int n0 = (wg % ntn) << 8;
  GEMM_SETUP()
  GEMM_MAINLOOP(MFMA16_S)
  // swapped C-layout: lane holds row = mb+mi*16+l16, cols nb+ni*16+quad*4 .. +3
  const int mb = m0 + wm * 128, nb = n0 + wn * 64;
  #pragma unroll
  for (int ni = 0; ni < 4; ++ni) {
    int colb = nb + ni * 16 + quad * 4;
    #pragma unroll
    for (int mi = 0; mi < 8; ++mi) {
      int row = mb + mi * 16 + l16;
      *(f32x4*)&Cout[(size_t)row * N + colb] = acc[mi][ni];
    }
  }
}

// ---- Fused QKV GEMM: Bt = [wqt|wkt|wvt] (N=3072). sec = n0>>10:
//   sec 0/1 -> Q/K bf16 [M][1024], swapped loop, ushort4 stores, per-col scale;
//   sec 2   -> V bf16 TRANSPOSED Vt[col*M+row], unswapped loop (verified r3 path).
__global__ __launch_bounds__(512, 2) void k_gemm_qkv(
    const u16* __restrict__ A, const u16* __restrict__ Bt,
    u16* __restrict__ Qo, u16* __restrict__ Ko, u16* __restrict__ Vt,
    const float* __restrict__ qsc, float ks, int M, int K) {
  __shared__ __align__(16) u16 lds[2][2][16384];
  const int tid = threadIdx.x;
  const int wave = tid >> 6, lane = tid & 63;
  const int l16 = lane & 15, quad = lane >> 4;
  const int wm = wave >> 2, wn = wave & 3;
  // 3x3 supergroup map: sg = 9 blocks covering 3 m-panels x 3 n-panels (L2 ~3MB).
  // grid 1800, chunk 225 = 25 sgs; sg-cols = 12/3 = 4; sg-rows = 150/3 = 50.
  const int q8 = (int)gridDim.x >> 3;             // 225
  const int wg = ((int)blockIdx.x & 7) * q8 + ((int)blockIdx.x >> 3);
  const int sg = wg / 9, lcl = wg % 9;
  const int m0 = ((sg >> 2) * 3 + lcl / 3) << 8;  // 0..149 panels
  const int n0 = ((sg & 3) * 3 + lcl % 3) << 8;   // 0..11 panels
  GEMM_SETUP()
  const int sec = n0 >> 10;
  const int mb = m0 + wm * 128;
  const int nbl = (n0 & 1023) + wn * 64;
  if (sec == 2) {
    GEMM_MAINLOOP(MFMA16_N)
    // unswapped layout: col = nbl+ni*16+l16, rows mb+mi*16+quad*4 .. +3 (contiguous in Vt)
    #pragma unroll
    for (int ni = 0; ni < 4; ++ni) {
      int col = nbl + ni * 16 + l16;
      #pragma unroll
      for (int mi = 0; mi < 8; ++mi) {
        int row = mb + mi * 16 + quad * 4;
        ushort4 o;
        o.x = f2bf(acc[mi][ni][0]);
        o.y = f2bf(acc[mi][ni][1]);
        o.z = f2bf(acc[mi][ni][2]);
        o.w = f2bf(acc[mi][ni][3]);
        *(ushort4*)&Vt[(size_t)col * M + row] = o;
      }
    }
  } else {
    GEMM_MAINLOOP(MFMA16_S)
    // swapped layout: row = mb+mi*16+l16, cols nbl+ni*16+quad*4 .. +3
    u16* Out = (sec == 0) ? Qo : Ko;
    #pragma unroll
    for (int ni = 0; ni < 4; ++ni) {
      int colb = nbl + ni * 16 + quad * 4;
      float4 sc;
      if (sec == 0) sc = *(const float4*)&qsc[colb];
      else { sc.x = ks; sc.y = ks; sc.z = ks; sc.w = ks; }
      #pragma unroll
      for (int mi = 0; mi < 8; ++mi) {
        int row = mb + mi * 16 + l16;
        ushort4 o;
        o.x = f2bf(acc[mi][ni][0] * sc.x);
        o.y = f2bf(acc[mi][ni][1] * sc.y);
        o.z = f2bf(acc[mi][ni][2] * sc.z);
        o.w = f2bf(acc[mi][ni][3] * sc.w);
        *(ushort4*)&Out[(size_t)row * 1024 + colb] = o;
      }
    }
  }
}

#undef GEMM_SETUP
#undef GEMM_MAINLOOP
#undef STAGE_A
#undef STAGE_B
#undef LOAD_A
#undef LOAD_B
#undef MFMA16_N
#undef MFMA16_S

// ---------------------------------------------------------------- attention (MFMA, persistent)
// unit = (b, n, h); CHUNK=12, PAST=12, CTX=24, P=25, D=128, SOFTCAP=50.
// q,k: [b*2400+s][1024] bf16 rows.  vt: TRANSPOSED [col][38400] bf16 (col = h*128+d), +16 u16 front slack.
// relkb: [32][1024] bf16 (rows 25..31 garbage, never used in output).
// C-layout: col = l16, row = quad*4+reg.  A-layout: A[m=l16][k=quad*8+j].
// Persistent: grid 1600 blocks -> exactly 4 iterations/block (25600 units / 4 waves).
// No barriers in the loop (LDS strictly per-wave; per-wave DS ops are in-order).
__global__ __launch_bounds__(256) void k_attn_mfma(
    const u16* __restrict__ q, const u16* __restrict__ k, const u16* __restrict__ vt,
    const u16* __restrict__ relkb, u16* __restrict__ ctx) {
  __shared__ float bdm_s[4][400];     // per-wave [16][25] row-major (flat reindex target)
  __shared__ u16 attnb[4][16 * 32];   // per-wave P matrix, A-layout staging

  const int tid = threadIdx.x;
  const int w = tid >> 6, lane = tid & 63;
  const int l16 = lane & 15, quad = lane >> 4;

  for (int id0 = (int)blockIdx.x * 4; id0 < 25600; id0 += (int)gridDim.x * 4) {
    const int id = id0 + w;                   // 0..25599
    const int b = id / 1600;
    const int rr = id % 1600;
    const int n = rr >> 3, h = rr & 7;
    const int s0 = n * 12;
    const size_t rowbase = (size_t)b * 2400;

    // ---- Q a-frags (m = l16 = q-row, k-chunks c: k = 32c + quad*8 + j)
    bf16x8 qf[4];
    {
      int sq = s0 + l16;
      if (sq > 2399) sq = 2399;  // pad q-rows read real data; outputs never stored
      const u16* qp = q + ((rowbase + sq) * 1024 + (size_t)h * 128 + quad * 8);
      #pragma unroll
      for (int c = 0; c < 4; ++c) qf[c] = *(const bf16x8*)(qp + 32 * c);
    }

    // ---- bd = Q @ rel_k^T  (2 p-tiles), store to LDS [16][25] for flat reindex
    #pragma unroll
    for (int pt = 0; pt < 2; ++pt) {
      int p = pt * 16 + l16;
      const u16* rp = relkb + ((size_t)p * 1024 + (size_t)h * 128 + quad * 8);
      f32x4 acc = {0.f, 0.f, 0.f, 0.f};
      #pragma unroll
      for (int c = 0; c < 4; ++c)
        acc = __builtin_amdgcn_mfma_f32_16x16x32_bf16(qf[c], *(const bf16x8*)(rp + 32 * c), acc, 0, 0, 0);
      if (p < 25) {
        #pragma unroll
        for (int r = 0; r < 4; ++r)
          bdm_s[w][(quad * 4 + r) * 25 + p] = acc[r];
      }
    }
    __threadfence_block();  // LDS write->read ordering within wave

    // ---- ac = Q @ K^T (2 t-tiles) + combine with shifted bd + softcap
    float l0[4], l1[4];
    #pragma unroll
    for (int kt = 0; kt < 2; ++kt) {
      int t = kt * 16 + l16;
      int sk = s0 - 12 + t;
      bool kvalid = ((unsigned)sk < 2400u);
      int ska = kvalid ? sk : 0;
      const u16* kp = k + ((rowbase + ska) * 1024 + (size_t)h * 128 + quad * 8);
      short km = kvalid ? (short)0xFFFF : (short)0;
      bf16x8 kmv = {km, km, km, km, km, km, km, km};
      f32x4 acc = {0.f, 0.f, 0.f, 0.f};
      #pragma unroll
      for (int c = 0; c < 4; ++c) {
        bf16x8 kf = *(const bf16x8*)(kp + 32 * c);
        kf &= kmv;  // zero-padded context rows: ac = 0, bd still enters softmax
        acc = __builtin_amdgcn_mfma_f32_16x16x32_bf16(qf[c], kf, acc, 0, 0, 0);
      }
      #pragma unroll
      for (int r = 0; r < 4; ++r) {
        float bd = bdm_s[w][(quad * 4 + r) * 24 + t];  // rel-shift = flat reindex
        float lg = tanhf((acc[r] + bd) * (1.0f / 50.0f)) * 50.0f;
        if (kt == 1 && l16 >= 8) lg = -INFINITY;  // t >= 24: outside CTX
        if (kt) l1[r] = lg; else l0[r] = lg;
      }
    }

    // ---- softmax over t (row q = quad*4+r lives in a 16-lane group)
    float at0[4], at1[4];
    #pragma unroll
    for (int r = 0; r < 4; ++r) {
      float m = fmaxf(l0[r], l1[r]);
      #pragma unroll
      for (int s = 1; s < 16; s <<= 1) m = fmaxf(m, __shfl_xor(m, s, 64));
      float e0 = __expf(l0[r] - m), e1 = __expf(l1[r] - m);
      float sum = e0 + e1;
      #pragma unroll
      for (int s = 1; s < 16; s <<= 1) sum += __shfl_xor(sum, s, 64);
      float inv = 1.0f / sum;
      at0[r] = e0 * inv;
      at1[r] = e1 * inv;
    }

    // ---- P: C-layout -> A-layout via LDS (bf16)
    #pragma unroll
    for (int r = 0; r < 4; ++r) {
      attnb[w][(quad * 4 + r) * 32 + l16] = f2bf(at0[r]);
      attnb[w][(quad * 4 + r) * 32 + 16 + l16] = f2bf(at1[r]);
    }
    __threadfence_block();
    bf16x8 paf = *(const bf16x8*)&attnb[w][l16 * 32 + quad * 8];

    // ---- PV: 8 d-tiles, B-frag = V^T[d][t] contiguous in vt; mask invalid s elements
    int slo = s0 - 12 + quad * 8;
    bf16x8 vmsk;
    #pragma unroll
    for (int j = 0; j < 8; ++j)
      vmsk[j] = ((unsigned)(slo + j) < 2400u) ? (short)0xFFFF : (short)0;

    f32x4 oacc[8];
    #pragma unroll
    for (int dt = 0; dt < 8; ++dt) {
      int col = h * 128 + dt * 16 + l16;
      const u16* vp = vt + ((size_t)col * 38400 + (long)(rowbase + s0 - 12 + quad * 8));
      ushort4 va = *(const ushort4*)vp;
      ushort4 vb = *(const ushort4*)(vp + 4);
      bf16x8 vf = {(short)va.x, (short)va.y, (short)va.z, (short)va.w,
                   (short)vb.x, (short)vb.y, (short)vb.z, (short)vb.w};
      vf &= vmsk;
      f32x4 z = {0.f, 0.f, 0.f, 0.f};
      oacc[dt] = __builtin_amdgcn_mfma_f32_16x16x32_bf16(paf, vf, z, 0, 0, 0);
    }

    // ---- store O (rows q = quad*4+r, only q<12 valid -> quads 0..2)
    if (quad < 3) {
      #pragma unroll
      for (int dt = 0; dt < 8; ++dt) {
        int col = h * 128 + dt * 16 + l16;
        #pragma unroll
        for (int r = 0; r < 4; ++r) {
          int qi = quad * 4 + r;
          ctx[(rowbase + s0 + qi) * 1024 + col] = f2bf(oacc[dt][r]);
        }
      }
    }
  }
}

// ---------------------------------------------------------------- launch

extern "C" void kernel_launch(void* const* d_in, const int* in_sizes, int n_in,
                              void* d_out, int out_size, void* d_ws, size_t ws_size,
                              hipStream_t stream) {
  const float* x       = (const float*)d_in[0];  // [16,2400,1024]
  const float* pos_emb = (const float*)d_in[1];  // [25,1024]
  const float* Wq      = (const float*)d_in[2];
  const float* Wk      = (const float*)d_in[3];
  const float* Wv      = (const float*)d_in[4];
  const float* Wpost   = (const float*)d_in[5];
  const float* Wrel    = (const float*)d_in[6];
  const float* pds     = (const float*)d_in[7];  // [128]
  float* out = (float*)d_out;

  const int M = 38400, HS = 1024;           // M = B*S = 16*2400
  const size_t XE = (size_t)M * HS;

  // workspace layout (u16 units)
  u16* xbf = (u16*)d_ws;                 // XE; reused as ctx after QKV GEMMs consume it
  u16* qbf = xbf + XE;                   // XE
  u16* kbf = qbf + XE;                   // XE
  u16* vt_alloc = kbf + XE;              // XE + 64 (slack for boundary-masked loads)
  u16* vt = vt_alloc + 16;
  u16* wqt = vt_alloc + XE + 64;         // wqt|wkt|wvt contiguous -> fused QKV Bt
  u16* wkt = wqt + (size_t)HS * HS;
  u16* wvt = wkt + (size_t)HS * HS;
  u16* wrt = wvt + (size_t)HS * HS;
  u16* wpt = wrt + (size_t)HS * HS;
  u16* relkb = wpt + (size_t)HS * HS;    // 32*1024 (rows 25..31 unwritten, harmless)
  float* qsc = (float*)(relkb + 32 * 1024);

  const double LN2 = 0.6931471805599453;
  const float QS = (float)((1.0 / sqrt(128.0)) / LN2);
  const float KS = (float)(log(1.0 + exp(1.0)) / LN2);

  // 1) x -> bf16
  k_f32_to_bf16<<<(int)(XE / 4 / 256), 256, 0, stream>>>(x, xbf, (int)(XE / 4));
  // 2) transpose weights -> bf16 [n][k]
  dim3 tg(32, 32);
  k_transpose_w<<<tg, 256, 0, stream>>>(Wq, wqt);
  k_transpose_w<<<tg, 256, 0, stream>>>(Wk, wkt);
  k_transpose_w<<<tg, 256, 0, stream>>>(Wv, wvt);
  k_transpose_w<<<tg, 256, 0, stream>>>(Wrel, wrt);
  k_transpose_w<<<tg, 256, 0, stream>>>(Wpost, wpt);
  // 3) per-column q scale
  k_qscale<<<4, 256, 0, stream>>>(pds, qsc, QS);
  // 4) rel_k = pos_emb @ Wrel -> bf16
  k_relk<<<dim3(4, 25), 256, 0, stream>>>(pos_emb, wrt, relkb);
  // 5) fused QKV projection: Bt = [wqt|wkt|wvt], N=3072, grid = 150*12 = 1800 (%8==0)
  k_gemm_qkv<<<(M / 256) * 12, 512, 0, stream>>>(xbf, wqt, qbf, kbf, vt, qsc, KS, M, HS);
  // 6) attention -> ctx (persistent, 1600 blocks = exactly 4 units/wave; reuses xbf)
  k_attn_mfma<<<1600, 256, 0, stream>>>(qbf, kbf, vt, relkb, xbf);
  // 7) out = ctx @ Wpost (fp32 out), grid = 150*4 = 600
  k_gemm256<<<(M / 256) * (HS / 256), 512, 0, stream>>>(xbf, wpt, out, M, HS, HS);
}

// Round 7
// 802.858 us; speedup vs baseline: 1.0358x; 1.0358x over previous
//
#include <hip/hip_runtime.h>
#include <hip/hip_bf16.h>
#include <cmath>

#define AS_GLOBAL __attribute__((address_space(1)))
#define AS_LDS    __attribute__((address_space(3)))

typedef __attribute__((ext_vector_type(8))) short bf16x8;
typedef __attribute__((ext_vector_type(4))) float f32x4;
typedef unsigned short u16;

__device__ __forceinline__ u16 f2bf(float f) {
  union { __hip_bfloat16 h; u16 u; } cv;
  cv.h = __float2bfloat16(f);
  return cv.u;
}
__device__ __forceinline__ float bf2f(u16 u) {
  union { unsigned u32; float f; } v;
  v.u32 = ((unsigned)u) << 16;
  return v.f;
}

// ---------------------------------------------------------------- prep kernels

__global__ void k_f32_to_bf16(const float* __restrict__ in, u16* __restrict__ out, int n4) {
  int i = blockIdx.x * 256 + threadIdx.x;
  if (i >= n4) return;
  float4 v = ((const float4*)in)[i];
  ushort4 o;
  o.x = f2bf(v.x); o.y = f2bf(v.y); o.z = f2bf(v.z); o.w = f2bf(v.w);
  ((ushort4*)out)[i] = o;
}

// out[n][k] = bf16(in[k][n]), 1024x1024
__global__ void k_transpose_w(const float* __restrict__ in, u16* __restrict__ out) {
  __shared__ float tile[32][33];
  const int tx = threadIdx.x & 31;
  const int ty = threadIdx.x >> 5;  // 0..7
  const int x0 = blockIdx.x * 32, y0 = blockIdx.y * 32;
  #pragma unroll
  for (int i = 0; i < 32; i += 8)
    tile[ty + i][tx] = in[(size_t)(y0 + ty + i) * 1024 + x0 + tx];
  __syncthreads();
  #pragma unroll
  for (int i = 0; i < 32; i += 8)
    out[(size_t)(x0 + ty + i) * 1024 + y0 + tx] = f2bf(tile[tx][ty + i]);
}

// qscale[n] = Q_SCALE * softplus(pds[n % 128]), n in [0,1024)
__global__ void k_qscale(const float* __restrict__ pds, float* __restrict__ qs, float qscale_c) {
  int n = blockIdx.x * 256 + threadIdx.x;
  float s = pds[n & 127];
  qs[n] = qscale_c * log1pf(expf(s));
}

// relkb[p][n] = bf16( sum_k pos[p][k] * Wrel[k][n] )  (wrt = Wrel^T bf16)
__global__ void k_relk(const float* __restrict__ pos, const u16* __restrict__ wrt,
                       u16* __restrict__ relkb) {
  __shared__ float prow[1024];
  const int tid = threadIdx.x;
  const int p = blockIdx.y;
  ((float4*)prow)[tid] = ((const float4*)(pos + (size_t)p * 1024))[tid];
  __syncthreads();
  int nn = blockIdx.x * 256 + tid;
  const u16* wr = wrt + (size_t)nn * 1024;
  float acc = 0.f;
  for (int kk = 0; kk < 1024; kk += 8) {
    ushort4 u0 = *(const ushort4*)(wr + kk);
    ushort4 u1 = *(const ushort4*)(wr + kk + 4);
    acc += bf2f(u0.x) * prow[kk + 0] + bf2f(u0.y) * prow[kk + 1]
         + bf2f(u0.z) * prow[kk + 2] + bf2f(u0.w) * prow[kk + 3]
         + bf2f(u1.x) * prow[kk + 4] + bf2f(u1.y) * prow[kk + 5]
         + bf2f(u1.z) * prow[kk + 6] + bf2f(u1.w) * prow[kk + 7];
  }
  relkb[(size_t)p * 1024 + nn] = f2bf(acc);
}

// ---------------------------------------------------------------- GEMM (256^2, 8-phase, A-once order)
// BM=BN=256, BK=64. 512 threads = 8 waves (2M x 4N), per-wave 128x64 output.
// LDS 128 KiB dbuf; granule swizzle g^=(row&7) on stage-source AND ds_read (rule 21).
// ROUND 7 CHANGE (single variable vs 798-verified r5 kernel): phase order per tile is
// (0,0),(0,1),(1,0),(1,1) with ALL FOUR B-halves held live (bfb[4][2], +16 VGPR) so
// every A/B fragment is ds_read exactly ONCE: 24 b128/tile/wave (was 32 — A(qm=0) was
// re-read). LDS-read cap rises 61% -> 81% of MFMA issue.
// vmcnt ledger (re-derived, per-thread GLD FIFO): prologue 16 GLD -> VMCNT(12);
// steady per half-tile: P0 end VMCNT(10) [retire B1], P1 end VMCNT(12) [retire A1],
// P2 end none, P3 end VMCNT(12) [retire next A0,B0]. Chunk restaged exactly one
// barrier after its last read (no WAR). Tail drains 10/8/4/2/0.
// Requires M%256==0, N%256==0, (K/64) even >=4, gridDim.x%8==0.

#define VMCNT(n) do { asm volatile("s_waitcnt vmcnt(" #n ")" ::: "memory"); \
                      __builtin_amdgcn_sched_barrier(0); } while (0)
#define BARF() do { asm volatile("" ::: "memory"); __builtin_amdgcn_s_barrier(); asm volatile("" ::: "memory"); } while (0)
#define GLD(SRC, DST) __builtin_amdgcn_global_load_lds((const AS_GLOBAL u16*)(SRC), (AS_LDS u16*)(DST), 16, 0, 0)
#define LDSA(d) ((AS_LDS char*)&lds[d][0][0])
#define LDSB(d) ((AS_LDS char*)&lds[d][1][0])

#define STAGE_A(d, h, t) do {                                                   \
  GLD(sA0 + (((size_t)(h)) << 6) * K + ((t) << 6), LDSA(d) + dA0 + ((h) << 13)); \
  GLD(sA1 + (((size_t)(h)) << 6) * K + ((t) << 6), LDSA(d) + dA1 + ((h) << 13)); \
} while (0)
#define STAGE_B(d, h, t) do {                                                   \
  GLD(sB0 + (((size_t)(h)) << 5) * K + ((t) << 6), LDSB(d) + dB0 + ((h) << 12)); \
  GLD(sB1 + (((size_t)(h)) << 5) * K + ((t) << 6), LDSB(d) + dB1 + ((h) << 12)); \
} while (0)

#define LOAD_A(d, qm) do {                                                       \
  _Pragma("unroll") for (int mi_ = 0; mi_ < 4; ++mi_) {                          \
    af[mi_][0] = *(const bf16x8*)&lds[d][0][abase + (((qm)*64 + mi_*16) << 6) + gk0]; \
    af[mi_][1] = *(const bf16x8*)&lds[d][0][abase + (((qm)*64 + mi_*16) << 6) + gk1]; \
  } } while (0)
// B-halves held live: qn half goes to bfb[qn*2 .. qn*2+1]
#define LOAD_B(d, qn) do {                                                       \
  _Pragma("unroll") for (int ni_ = 0; ni_ < 2; ++ni_) {                          \
    bfb[(qn)*2+ni_][0] = *(const bf16x8*)&lds[d][1][bbase + (((qn)*32 + ni_*16) << 6) + gk0]; \
    bfb[(qn)*2+ni_][1] = *(const bf16x8*)&lds[d][1][bbase + (((qn)*32 + ni_*16) << 6) + gk1]; \
  } } while (0)
#define MFMA16(qm, qn) do {                                                      \
  __builtin_amdgcn_s_setprio(1);                                                 \
  _Pragma("unroll") for (int mi_ = 0; mi_ < 4; ++mi_)                            \
  _Pragma("unroll") for (int ni_ = 0; ni_ < 2; ++ni_) {                          \
    acc[(qm)*4+mi_][(qn)*2+ni_] = __builtin_amdgcn_mfma_f32_16x16x32_bf16(       \
        af[mi_][0], bfb[(qn)*2+ni_][0], acc[(qm)*4+mi_][(qn)*2+ni_], 0, 0, 0);   \
    acc[(qm)*4+mi_][(qn)*2+ni_] = __builtin_amdgcn_mfma_f32_16x16x32_bf16(       \
        af[mi_][1], bfb[(qn)*2+ni_][1], acc[(qm)*4+mi_][(qn)*2+ni_], 0, 0, 0);   \
  }                                                                              \
  __builtin_amdgcn_s_setprio(0); } while (0)

// Full pipeline: prologue (read-order staging) + steady loop + peeled tail.
#define GEMM_MAINLOOP()                                                          \
  STAGE_A(0, 0, 0); STAGE_B(0, 0, 0); STAGE_B(0, 1, 0); STAGE_A(0, 1, 0);        \
  STAGE_A(1, 0, 1); STAGE_B(1, 0, 1); STAGE_B(1, 1, 1); STAGE_A(1, 1, 1);        \
  VMCNT(12);  BARF();                                                            \
  const int nk = K >> 6;                                                         \
  for (int i = 0; i < (nk >> 1) - 1; ++i) {                                      \
    const int t2 = 2 * i + 2, t3 = 2 * i + 3;                                    \
    /* P0: read A0,B0 of buf0 */                                                 \
    LOAD_A(0, 0); LOAD_B(0, 0);                                                  \
    BARF(); MFMA16(0, 0); VMCNT(10); BARF();                                     \
    /* P1: read B1; stage next A0,B0 (freed after P0) */                         \
    LOAD_B(0, 1);                                                                \
    STAGE_A(0, 0, t2); STAGE_B(0, 0, t2);                                        \
    BARF(); MFMA16(0, 1); VMCNT(12); BARF();                                     \
    /* P2: read A1; stage next B1 (freed after P1) */                            \
    LOAD_A(0, 1);                                                                \
    STAGE_B(0, 1, t2);                                                           \
    BARF(); MFMA16(1, 0); BARF();                                                \
    /* P3: stage next A1 (freed after P2) */                                     \
    STAGE_A(0, 1, t2);                                                           \
    BARF(); MFMA16(1, 1); VMCNT(12); BARF();                                     \
    /* P4..P7: mirror on buf1 */                                                 \
    LOAD_A(1, 0); LOAD_B(1, 0);                                                  \
    BARF(); MFMA16(0, 0); VMCNT(10); BARF();                                     \
    LOAD_B(1, 1);                                                                \
    STAGE_A(1, 0, t3); STAGE_B(1, 0, t3);                                        \
    BARF(); MFMA16(0, 1); VMCNT(12); BARF();                                     \
    LOAD_A(1, 1);                                                                \
    STAGE_B(1, 1, t3);                                                           \
    BARF(); MFMA16(1, 0); BARF();                                                \
    STAGE_A(1, 1, t3);                                                           \
    BARF(); MFMA16(1, 1); VMCNT(12); BARF();                                     \
  }                                                                              \
  {                                                                              \
    /* tail: tiles nk-2 (buf0), nk-1 (buf1), no staging; drains 10/8/4/2/0 */    \
    LOAD_A(0, 0); LOAD_B(0, 0);                                                  \
    BARF(); MFMA16(0, 0); VMCNT(10); BARF();                                     \
    LOAD_B(0, 1);                                                                \
    BARF(); MFMA16(0, 1); VMCNT(8); BARF();                                      \
    LOAD_A(0, 1);                                                                \
    BARF(); MFMA16(1, 0); MFMA16(1, 1); VMCNT(4); BARF();                        \
    LOAD_A(1, 0); LOAD_B(1, 0);                                                  \
    BARF(); MFMA16(0, 0); VMCNT(2); BARF();                                      \
    LOAD_B(1, 1);                                                                \
    BARF(); MFMA16(0, 1); VMCNT(0); BARF();                                      \
    LOAD_A(1, 1);                                                                \
    BARF(); MFMA16(1, 0); MFMA16(1, 1);                                          \
  }

// Common per-thread setup (indices, staging pointers, acc init).
#define GEMM_SETUP(NTN)                                                          \
  __shared__ __align__(16) u16 lds[2][2][16384];                                 \
  const int tid = threadIdx.x;                                                   \
  const int wave = tid >> 6, lane = tid & 63;                                    \
  const int l16 = lane & 15, quad = lane >> 4;                                   \
  const int wm = wave >> 2, wn = wave & 3;                                       \
  const int q8 = (int)gridDim.x >> 3;                                            \
  const int wg = ((int)blockIdx.x & 7) * q8 + ((int)blockIdx.x >> 3);            \
  const int m0 = (wg / (NTN)) << 8;                                              \
  const int n0 = (wg % (NTN)) << 8;                                              \
  const int sx = l16 & 7;                                                        \
  const int gk0 = (quad ^ sx) << 3;                                              \
  const int gk1 = ((4 + quad) ^ sx) << 3;                                        \
  const int abase = (wm * 128 + l16) << 6;                                       \
  const int bbase = (wn * 64 + l16) << 6;                                        \
  const int rl0 = tid >> 3, g0 = tid & 7;                                        \
  const int rl1 = rl0 + 64;                                                      \
  const int swz0 = (g0 ^ (rl0 & 7)) << 3;                                        \
  const int rbA0 = ((rl0 >> 6) << 7) + (rl0 & 63);                               \
  const int rbA1 = ((rl1 >> 6) << 7) + (rl1 & 63);                               \
  const int rbB0 = ((rl0 >> 5) << 6) + (rl0 & 31);                               \
  const int rbB1 = ((rl1 >> 5) << 6) + (rl1 & 31);                               \
  const u16* sA0 = A + (size_t)(m0 + rbA0) * K + swz0;                           \
  const u16* sA1 = A + (size_t)(m0 + rbA1) * K + swz0;                           \
  const u16* sB0 = Bt + (size_t)(n0 + rbB0) * K + swz0;                          \
  const u16* sB1 = Bt + (size_t)(n0 + rbB1) * K + swz0;                          \
  const int dA0 = (rbA0 << 7) + (g0 << 4);                                       \
  const int dA1 = (rbA1 << 7) + (g0 << 4);                                       \
  const int dB0 = (rbB0 << 7) + (g0 << 4);                                       \
  const int dB1 = (rbB1 << 7) + (g0 << 4);                                       \
  f32x4 acc[8][4];                                                               \
  _Pragma("unroll") for (int i = 0; i < 8; ++i)                                  \
    _Pragma("unroll") for (int j = 0; j < 4; ++j) {                              \
      f32x4 z = {0.f, 0.f, 0.f, 0.f};                                            \
      acc[i][j] = z;                                                             \
    }                                                                            \
  bf16x8 af[4][2], bfb[4][2];

// ---- Wpost GEMM: C fp32 row-major [M][N] (798-verified epilogue)
__global__ __launch_bounds__(512, 2) void k_gemm256(
    const u16* __restrict__ A, const u16* __restrict__ Bt, float* __restrict__ Cout,
    int M, int N, int K) {
  GEMM_SETUP(N >> 8)
  GEMM_MAINLOOP()
  const int mb = m0 + wm * 128, nb = n0 + wn * 64;
  #pragma unroll
  for (int ni = 0; ni < 4; ++ni) {
    int col = nb + ni * 16 + l16;
    #pragma unroll
    for (int mi = 0; mi < 8; ++mi) {
      int row = mb + mi * 16 + quad * 4;
      #pragma unroll
      for (int r = 0; r < 4; ++r)
        Cout[(size_t)(row + r) * N + col] = acc[mi][ni][r];
    }
  }
}

// ---- Fused QKV GEMM: Bt = [wqt|wkt|wvt] (N=3072), n-fastest map (798-verified).
//   sec 0 -> Q bf16 [M][1024] * qsc[col];  sec 1 -> K bf16 [M][1024] * ks;
//   sec 2 -> V bf16 TRANSPOSED Vt[col*M + row].
__global__ __launch_bounds__(512, 2) void k_gemm_qkv(
    const u16* __restrict__ A, const u16* __restrict__ Bt,
    u16* __restrict__ Qo, u16* __restrict__ Ko, u16* __restrict__ Vt,
    const float* __restrict__ qsc, float ks, int M, int K) {
  GEMM_SETUP(12)
  GEMM_MAINLOOP()
  const int sec = n0 >> 10;
  const int mb = m0 + wm * 128;
  const int nbl = (n0 & 1023) + wn * 64;
  if (sec == 2) {
    #pragma unroll
    for (int ni = 0; ni < 4; ++ni) {
      int col = nbl + ni * 16 + l16;
      #pragma unroll
      for (int mi = 0; mi < 8; ++mi) {
        int row = mb + mi * 16 + quad * 4;
        ushort4 o;
        o.x = f2bf(acc[mi][ni][0]);
        o.y = f2bf(acc[mi][ni][1]);
        o.z = f2bf(acc[mi][ni][2]);
        o.w = f2bf(acc[mi][ni][3]);
        *(ushort4*)&Vt[(size_t)col * M + row] = o;
      }
    }
  } else {
    u16* Out = (sec == 0) ? Qo : Ko;
    #pragma unroll
    for (int ni = 0; ni < 4; ++ni) {
      int col = nbl + ni * 16 + l16;
      float cs = (sec == 0) ? qsc[col] : ks;
      #pragma unroll
      for (int mi = 0; mi < 8; ++mi) {
        int row = mb + mi * 16 + quad * 4;
        #pragma unroll
        for (int r = 0; r < 4; ++r)
          Out[(size_t)(row + r) * 1024 + col] = f2bf(acc[mi][ni][r] * cs);
      }
    }
  }
}

#undef GEMM_SETUP
#undef GEMM_MAINLOOP
#undef STAGE_A
#undef STAGE_B
#undef LOAD_A
#undef LOAD_B
#undef MFMA16

// ---------------------------------------------------------------- attention (MFMA, persistent)
// unit = (b, n, h); CHUNK=12, PAST=12, CTX=24, P=25, D=128, SOFTCAP=50.
// q,k: [b*2400+s][1024] bf16 rows.  vt: TRANSPOSED [col][38400] bf16 (col = h*128+d), +16 u16 front slack.
// relkb: [32][1024] bf16 (rows 25..31 garbage, never used in output).
// C-layout: col = l16, row = quad*4+reg.  A-layout: A[m=l16][k=quad*8+j].
// Persistent: grid 2048 blocks, each wave grid-strides over units (798-verified).
__global__ __launch_bounds__(256) void k_attn_mfma(
    const u16* __restrict__ q, const u16* __restrict__ k, const u16* __restrict__ vt,
    const u16* __restrict__ relkb, u16* __restrict__ ctx) {
  __shared__ float bdm_s[4][400];     // per-wave [16][25] row-major (flat reindex target)
  __shared__ u16 attnb[4][16 * 32];   // per-wave P matrix, A-layout staging

  const int tid = threadIdx.x;
  const int w = tid >> 6, lane = tid & 63;
  const int l16 = lane & 15, quad = lane >> 4;

  for (int id0 = (int)blockIdx.x * 4; id0 < 25600; id0 += (int)gridDim.x * 4) {
    const int id = id0 + w;                   // 0..25599
    const int b = id / 1600;
    const int rr = id % 1600;
    const int n = rr >> 3, h = rr & 7;
    const int s0 = n * 12;
    const size_t rowbase = (size_t)b * 2400;

    // ---- Q a-frags (m = l16 = q-row, k-chunks c: k = 32c + quad*8 + j)
    bf16x8 qf[4];
    {
      int sq = s0 + l16;
      if (sq > 2399) sq = 2399;  // pad q-rows read real data; outputs never stored
      const u16* qp = q + ((rowbase + sq) * 1024 + (size_t)h * 128 + quad * 8);
      #pragma unroll
      for (int c = 0; c < 4; ++c) qf[c] = *(const bf16x8*)(qp + 32 * c);
    }

    // ---- bd = Q @ rel_k^T  (2 p-tiles), store to LDS [16][25] for flat reindex
    #pragma unroll
    for (int pt = 0; pt < 2; ++pt) {
      int p = pt * 16 + l16;
      const u16* rp = relkb + ((size_t)p * 1024 + (size_t)h * 128 + quad * 8);
      f32x4 acc = {0.f, 0.f, 0.f, 0.f};
      #pragma unroll
      for (int c = 0; c < 4; ++c)
        acc = __builtin_amdgcn_mfma_f32_16x16x32_bf16(qf[c], *(const bf16x8*)(rp + 32 * c), acc, 0, 0, 0);
      if (p < 25) {
        #pragma unroll
        for (int r = 0; r < 4; ++r)
          bdm_s[w][(quad * 4 + r) * 25 + p] = acc[r];
      }
    }
    __threadfence_block();  // LDS write->read ordering within wave

    // ---- ac = Q @ K^T (2 t-tiles) + combine with shifted bd + softcap
    float l0[4], l1[4];
    #pragma unroll
    for (int kt = 0; kt < 2; ++kt) {
      int t = kt * 16 + l16;
      int sk = s0 - 12 + t;
      bool kvalid = ((unsigned)sk < 2400u);
      int ska = kvalid ? sk : 0;
      const u16* kp = k + ((rowbase + ska) * 1024 + (size_t)h * 128 + quad * 8);
      short km = kvalid ? (short)0xFFFF : (short)0;
      bf16x8 kmv = {km, km, km, km, km, km, km, km};
      f32x4 acc = {0.f, 0.f, 0.f, 0.f};
      #pragma unroll
      for (int c = 0; c < 4; ++c) {
        bf16x8 kf = *(const bf16x8*)(kp + 32 * c);
        kf &= kmv;  // zero-padded context rows: ac = 0, bd still enters softmax
        acc = __builtin_amdgcn_mfma_f32_16x16x32_bf16(qf[c], kf, acc, 0, 0, 0);
      }
      #pragma unroll
      for (int r = 0; r < 4; ++r) {
        float bd = bdm_s[w][(quad * 4 + r) * 24 + t];  // rel-shift = flat reindex
        float lg = tanhf((acc[r] + bd) * (1.0f / 50.0f)) * 50.0f;
        if (kt == 1 && l16 >= 8) lg = -INFINITY;  // t >= 24: outside CTX
        if (kt) l1[r] = lg; else l0[r] = lg;
      }
    }

    // ---- softmax over t (row q = quad*4+r lives in a 16-lane group)
    float at0[4], at1[4];
    #pragma unroll
    for (int r = 0; r < 4; ++r) {
      float m = fmaxf(l0[r], l1[r]);
      #pragma unroll
      for (int s = 1; s < 16; s <<= 1) m = fmaxf(m, __shfl_xor(m, s, 64));
      float e0 = __expf(l0[r] - m), e1 = __expf(l1[r] - m);
      float sum = e0 + e1;
      #pragma unroll
      for (int s = 1; s < 16; s <<= 1) sum += __shfl_xor(sum, s, 64);
      float inv = 1.0f / sum;
      at0[r] = e0 * inv;
      at1[r] = e1 * inv;
    }

    // ---- P: C-layout -> A-layout via LDS (bf16)
    #pragma unroll
    for (int r = 0; r < 4; ++r) {
      attnb[w][(quad * 4 + r) * 32 + l16] = f2bf(at0[r]);
      attnb[w][(quad * 4 + r) * 32 + 16 + l16] = f2bf(at1[r]);
    }
    __threadfence_block();
    bf16x8 paf = *(const bf16x8*)&attnb[w][l16 * 32 + quad * 8];

    // ---- PV: 8 d-tiles, B-frag = V^T[d][t] contiguous in vt; mask invalid s elements
    int slo = s0 - 12 + quad * 8;
    bf16x8 vmsk;
    #pragma unroll
    for (int j = 0; j < 8; ++j)
      vmsk[j] = ((unsigned)(slo + j) < 2400u) ? (short)0xFFFF : (short)0;

    f32x4 oacc[8];
    #pragma unroll
    for (int dt = 0; dt < 8; ++dt) {
      int col = h * 128 + dt * 16 + l16;
      const u16* vp = vt + ((size_t)col * 38400 + (long)(rowbase + s0 - 12 + quad * 8));
      ushort4 va = *(const ushort4*)vp;
      ushort4 vb = *(const ushort4*)(vp + 4);
      bf16x8 vf = {(short)va.x, (short)va.y, (short)va.z, (short)va.w,
                   (short)vb.x, (short)vb.y, (short)vb.z, (short)vb.w};
      vf &= vmsk;
      f32x4 z = {0.f, 0.f, 0.f, 0.f};
      oacc[dt] = __builtin_amdgcn_mfma_f32_16x16x32_bf16(paf, vf, z, 0, 0, 0);
    }

    // ---- store O (rows q = quad*4+r, only q<12 valid -> quads 0..2)
    if (quad < 3) {
      #pragma unroll
      for (int dt = 0; dt < 8; ++dt) {
        int col = h * 128 + dt * 16 + l16;
        #pragma unroll
        for (int r = 0; r < 4; ++r) {
          int qi = quad * 4 + r;
          ctx[(rowbase + s0 + qi) * 1024 + col] = f2bf(oacc[dt][r]);
        }
      }
    }
  }
}

// ---------------------------------------------------------------- launch

extern "C" void kernel_launch(void* const* d_in, const int* in_sizes, int n_in,
                              void* d_out, int out_size, void* d_ws, size_t ws_size,
                              hipStream_t stream) {
  const float* x       = (const float*)d_in[0];  // [16,2400,1024]
  const float* pos_emb = (const float*)d_in[1];  // [25,1024]
  const float* Wq      = (const float*)d_in[2];
  const float* Wk      = (const float*)d_in[3];
  const float* Wv      = (const float*)d_in[4];
  const float* Wpost   = (const float*)d_in[5];
  const float* Wrel    = (const float*)d_in[6];
  const float* pds     = (const float*)d_in[7];  // [128]
  float* out = (float*)d_out;

  const int M = 38400, HS = 1024;           // M = B*S = 16*2400
  const size_t XE = (size_t)M * HS;

  // workspace layout (u16 units)
  u16* xbf = (u16*)d_ws;                 // XE; reused as ctx after QKV GEMMs consume it
  u16* qbf = xbf + XE;                   // XE
  u16* kbf = qbf + XE;                   // XE
  u16* vt_alloc = kbf + XE;              // XE + 64 (slack for boundary-masked loads)
  u16* vt = vt_alloc + 16;
  u16* wqt = vt_alloc + XE + 64;         // wqt|wkt|wvt contiguous -> fused QKV Bt
  u16* wkt = wqt + (size_t)HS * HS;
  u16* wvt = wkt + (size_t)HS * HS;
  u16* wrt = wvt + (size_t)HS * HS;
  u16* wpt = wrt + (size_t)HS * HS;
  u16* relkb = wpt + (size_t)HS * HS;    // 32*1024 (rows 25..31 unwritten, harmless)
  float* qsc = (float*)(relkb + 32 * 1024);

  const double LN2 = 0.6931471805599453;
  const float QS = (float)((1.0 / sqrt(128.0)) / LN2);
  const float KS = (float)(log(1.0 + exp(1.0)) / LN2);

  // 1) x -> bf16
  k_f32_to_bf16<<<(int)(XE / 4 / 256), 256, 0, stream>>>(x, xbf, (int)(XE / 4));
  // 2) transpose weights -> bf16 [n][k]
  dim3 tg(32, 32);
  k_transpose_w<<<tg, 256, 0, stream>>>(Wq, wqt);
  k_transpose_w<<<tg, 256, 0, stream>>>(Wk, wkt);
  k_transpose_w<<<tg, 256, 0, stream>>>(Wv, wvt);
  k_transpose_w<<<tg, 256, 0, stream>>>(Wrel, wrt);
  k_transpose_w<<<tg, 256, 0, stream>>>(Wpost, wpt);
  // 3) per-column q scale
  k_qscale<<<4, 256, 0, stream>>>(pds, qsc, QS);
  // 4) rel_k = pos_emb @ Wrel -> bf16
  k_relk<<<dim3(4, 25), 256, 0, stream>>>(pos_emb, wrt, relkb);
  // 5) fused QKV projection: Bt = [wqt|wkt|wvt], N=3072, grid = 150*12 = 1800 (%8==0)
  k_gemm_qkv<<<(M / 256) * 12, 512, 0, stream>>>(xbf, wqt, qbf, kbf, vt, qsc, KS, M, HS);
  // 6) attention -> ctx (persistent, 2048 blocks; reuses xbf region)
  k_attn_mfma<<<2048, 256, 0, stream>>>(qbf, kbf, vt, relkb, xbf);
  // 7) out = ctx @ Wpost (fp32 out), grid = 150*4 = 600
  k_gemm256<<<(M / 256) * (HS / 256), 512, 0, stream>>>(xbf, wpt, out, M, HS, HS);
}